// Round 6
// baseline (260.745 us; speedup 1.0000x reference)
//
#include <hip/hip_runtime.h>
#include <cstdint>
#include <cstddef>

// Problem constants (K=2048 tokens, D=128 feat, E=64 hidden)
#define KTOT 2048
#define DDIM 128
#define EDIM 64
#define RPB  4   // output rows per block in edge kernel
#define KPB  4   // z-rows per block in projection kernel

#define LOG2E 1.44269504088896f

typedef float v2f __attribute__((ext_vector_type(2)));

// ---------------------------------------------------------------------------
// Kernel A: per row k and unit e (log2-domain t = (z@W1+b)*log2e):
//   hiw[k,e] = t_i * w2[e]      Ei[k,e] = 2^-t_i        (i-side)
//   hjw[k,e] = t_j * w2[e]      Ej[k,e] = 2^-t_j        (j-side)
// Folds W2 AND the exponential into the O(K*E) precompute, so the O(K^2*E)
// edge loop needs no transcendentals except one shared rcp per 8 elems:
//   silu-term sum = sum_e (hiw+hjw) / (1 + Ei*Ej)
// b2 is a row-constant in the logits -> cancels in softmax -> skipped.
// ---------------------------------------------------------------------------
__global__ void proj_kernel(const float* __restrict__ z,
                            const float* __restrict__ W1,
                            const float* __restrict__ b1,
                            const float* __restrict__ w2,
                            float* __restrict__ hiw, float* __restrict__ Ei,
                            float* __restrict__ hjw, float* __restrict__ Ej) {
  __shared__ float zrow[KPB][DDIM];
  const int t  = threadIdx.x;            // 0..127
  const int k0 = blockIdx.x * KPB;
#pragma unroll
  for (int r = 0; r < KPB; ++r) zrow[r][t] = z[(size_t)(k0 + r) * DDIM + t];
  __syncthreads();

  const int  e    = t & 63;
  const bool isHj = (t >= 64);           // wave-uniform (wave0 = i, wave1 = j)
  const float* Wcol = W1 + (isHj ? DDIM * EDIM : 0) + e;

  float acc[KPB];
  const float binit = isHj ? 0.0f : b1[e];
#pragma unroll
  for (int r = 0; r < KPB; ++r) acc[r] = binit;

#pragma unroll 4
  for (int d = 0; d < DDIM; ++d) {
    const float w = Wcol[(size_t)d * EDIM];   // coalesced 256B per wave
#pragma unroll
    for (int r = 0; r < KPB; ++r) acc[r] = fmaf(zrow[r][d], w, acc[r]);
  }

  const float wv = w2[e];
  float* dw = isHj ? hjw : hiw;
  float* dE = isHj ? Ej  : Ei;
#pragma unroll
  for (int r = 0; r < KPB; ++r) {
    const float tv = acc[r] * LOG2E;
    dw[(size_t)(k0 + r) * EDIM + e] = tv * wv;
    dE[(size_t)(k0 + r) * EDIM + e] = __builtin_amdgcn_exp2f(-tv);
  }
}

// ---------------------------------------------------------------------------
// Quad numerator/denominator for the shared-rcp tree (NO transcendentals):
//   u_k = hiw_k + hjw_k          (pk_add)
//   d_k = 1 + Ei_k*Ej_k          (pk_fma)
//   (Nq, Dq) s.t. sum_k u_k/d_k = Nq/Dq over the 4 elements.
// ---------------------------------------------------------------------------
__device__ __forceinline__ void quad_nd(const float4 hw, const float4 he,
                                        const float4 jw, const float4 je,
                                        float& Nq, float& Dq) {
  const v2f u01 = (v2f){hw.x, hw.y} + (v2f){jw.x, jw.y};
  const v2f u23 = (v2f){hw.z, hw.w} + (v2f){jw.z, jw.w};
  const v2f d01 = (v2f){he.x, he.y} * (v2f){je.x, je.y} + 1.0f;  // pk_fma
  const v2f d23 = (v2f){he.z, he.w} * (v2f){je.z, je.w} + 1.0f;
  const float n01 = fmaf(u01.x, d01.y, u01.y * d01.x);
  const float n23 = fmaf(u23.x, d23.y, u23.y * d23.x);
  const float p01 = d01.x * d01.y;
  const float p23 = d23.x * d23.y;
  Nq = fmaf(n01, p23, n23 * p01);
  Dq = p01 * p23;
}

// ---------------------------------------------------------------------------
// Kernel B: 1024 threads (16 waves), block owns RPB=4 output rows.
// Grid = 512 blocks = exactly 2 blocks/CU x 16 waves = 32 waves/CU (100%
// occupancy, perfectly balanced). Traffic unchanged vs RPB=4/512-thread
// (each block still reads the j-tables once: 1 MB -> 512 MB total ~ 20 TB/s
// L2, under the 34.5 ceiling).
// Lane layout: sub = lane&7 -> e-octet (e = sub*8..+7, two float4 quads)
//              jg  = lane>>3 -> j within the wave's 8-j group
// 16 waves x 8 j = 128 j per iteration -> 16 iterations; j streams double-
// buffered in registers. Inner loop: 0 exp2, 1 rcp per 8 elems. 3-shfl
// e-group reduce. Max-free softmax epilogue (logits ~ +-6 in log2 domain).
// ---------------------------------------------------------------------------
__global__ __launch_bounds__(1024, 8) void edge_softmax_kernel(
    const float* __restrict__ hiw_, const float* __restrict__ Ei_,
    const float* __restrict__ hjw_, const float* __restrict__ Ej_,
    float* __restrict__ out) {
  __shared__ float logits[RPB][KTOT];    // 32 KB
  __shared__ float ps[RPB][4];           // cross-wave sum partials

  const int tid  = threadIdx.x;
  const int lane = tid & 63;
  const int wave = tid >> 6;             // 0..15
  const int sub  = lane & 7;             // e-octet index
  const int jg   = lane >> 3;            // 0..7
  const int i0   = blockIdx.x * RPB;

  // Row-constant fragments: 16 float4
  float4 hwA[RPB], hwB[RPB], heA[RPB], heB[RPB];
#pragma unroll
  for (int r = 0; r < RPB; ++r) {
    const size_t o = (size_t)(i0 + r) * EDIM + sub * 8;
    hwA[r] = *reinterpret_cast<const float4*>(hiw_ + o);
    hwB[r] = *reinterpret_cast<const float4*>(hiw_ + o + 4);
    heA[r] = *reinterpret_cast<const float4*>(Ei_ + o);
    heB[r] = *reinterpret_cast<const float4*>(Ei_ + o + 4);
  }

  const int jbase = wave * 8 + jg;       // this lane's j at iter 0 (0..127)
  const float* pjw = hjw_ + (size_t)jbase * EDIM + sub * 8;
  const float* pje = Ej_  + (size_t)jbase * EDIM + sub * 8;

  float4 jwA = *reinterpret_cast<const float4*>(pjw);
  float4 jwB = *reinterpret_cast<const float4*>(pjw + 4);
  float4 jeA = *reinterpret_cast<const float4*>(pje);
  float4 jeB = *reinterpret_cast<const float4*>(pje + 4);

  for (int it = 0; it < KTOT / 128; ++it) {
    const float4 cwA = jwA, cwB = jwB, ceA = jeA, ceB = jeB;
    if (it + 1 < KTOT / 128) {           // prefetch next j-row under compute
      const size_t off = (size_t)(it + 1) * 128 * EDIM;
      jwA = *reinterpret_cast<const float4*>(pjw + off);
      jwB = *reinterpret_cast<const float4*>(pjw + off + 4);
      jeA = *reinterpret_cast<const float4*>(pje + off);
      jeB = *reinterpret_cast<const float4*>(pje + off + 4);
    }
    const int j = jbase + it * 128;
#pragma unroll
    for (int r = 0; r < RPB; ++r) {
      float N0, D0, N1, D1;
      quad_nd(hwA[r], heA[r], cwA, ceA, N0, D0);
      quad_nd(hwB[r], heB[r], cwB, ceB, N1, D1);
      const float rD = __builtin_amdgcn_rcpf(D0 * D1);
      float a = fmaf(N0, D1, N1 * D0) * rD;
      // butterfly over the 8-lane e-group
      a += __shfl_xor(a, 1);
      a += __shfl_xor(a, 2);
      a += __shfl_xor(a, 4);
      if (sub == 0) logits[r][j] = a;    // 8 lanes store 8 consecutive floats
    }
  }
  __syncthreads();

  // Max-free softmax: wave w -> row (w>>2), quarter (w&3) of 512 elems.
  const int r = wave >> 2;
  const int q = wave & 3;
  float* lrow = logits[r];
  const int base = q * 512;

  float ssum = 0.0f;
#pragma unroll
  for (int t = 0; t < 8; ++t) {
    const int k = base + t * 64 + lane;
    const float ev = __builtin_amdgcn_exp2f(lrow[k]);  // log2-domain
    lrow[k] = ev;
    ssum += ev;
  }
#pragma unroll
  for (int off = 32; off; off >>= 1) ssum += __shfl_xor(ssum, off);
  if (lane == 0) ps[r][q] = ssum;
  __syncthreads();
  const float rinv = 1.0f / (ps[r][0] + ps[r][1] + ps[r][2] + ps[r][3]);

  float* orow = out + (size_t)(i0 + r) * KTOT;
#pragma unroll
  for (int t = 0; t < 2; ++t) {
    const int k4 = q * 128 + t * 64 + lane;
    float4 v = *reinterpret_cast<const float4*>(&lrow[k4 * 4]);
    v.x *= rinv; v.y *= rinv; v.z *= rinv; v.w *= rinv;
    *reinterpret_cast<float4*>(&orow[k4 * 4]) = v;  // coalesced 1KB/wave
  }
}

// ---------------------------------------------------------------------------
extern "C" void kernel_launch(void* const* d_in, const int* in_sizes, int n_in,
                              void* d_out, int out_size, void* d_ws, size_t ws_size,
                              hipStream_t stream) {
  const float* z  = (const float*)d_in[0];
  const float* W1 = (const float*)d_in[1];
  const float* b1 = (const float*)d_in[2];
  const float* W2 = (const float*)d_in[3];
  // d_in[4] = b2: uniform logit shift, cancels in softmax.
  float* out = (float*)d_out;

  float* hiw = (float*)d_ws;                      // 4 arrays x 512 KB = 2 MB
  float* Ei  = hiw + (size_t)KTOT * EDIM;
  float* hjw = Ei  + (size_t)KTOT * EDIM;
  float* Ej  = hjw + (size_t)KTOT * EDIM;

  hipLaunchKernelGGL(proj_kernel, dim3(KTOT / KPB), dim3(DDIM), 0, stream,
                     z, W1, b1, W2, hiw, Ei, hjw, Ej);
  hipLaunchKernelGGL(edge_softmax_kernel, dim3(KTOT / RPB), dim3(1024), 0, stream,
                     hiw, Ei, hjw, Ej, out);
}